// Round 22
// baseline (379.627 us; speedup 1.0000x reference)
//
#include <hip/hip_runtime.h>

#define NP 4096
#define BB 2

typedef __attribute__((ext_vector_type(8))) short short8;
typedef __attribute__((ext_vector_type(4))) float f32x4;
#define MFMA_BF16 __builtin_amdgcn_mfma_f32_16x16x32_bf16

__device__ __forceinline__ float wsum(float v){
  #pragma unroll
  for (int o = 32; o; o >>= 1) v += __shfl_down(v, o, 64);
  return v;
}
__device__ __forceinline__ unsigned short f2bf(float x){
  unsigned int u = __float_as_uint(x);
  return (unsigned short)((u + 0x7fffu + ((u >> 16) & 1u)) >> 16);
}
__device__ __forceinline__ float bfh(unsigned short h){
  return __uint_as_float((unsigned int)h << 16);
}
__device__ __forceinline__ float bf2f(unsigned short h, unsigned short l){
  return bfh(h) + bfh(l);
}
__device__ __forceinline__ short8 ld8(const unsigned short* p){
  return *(const short8*)p;
}

// ---------------------------------------------------------------------------
// Pre-split fp32 weights -> bf16 hi/lo, LDS-ready layout, row-range variant.
__global__ __launch_bounds__(256) void k_wsplit(
    const float* __restrict__ src, size_t src_ls,
    unsigned short* __restrict__ dh, unsigned short* __restrict__ dl,
    size_t dst_ls, int O, int O_span, int O_pad, int o_base, int Cin, int ldsrc)
{
  const int y = blockIdx.y;
  const int idx = blockIdx.x * 256 + threadIdx.x;
  const int chunks = (Cin >> 6) * O_span * 8;
  if (idx >= chunks) return;
  const int qs = idx & 7;
  const int ol = (idx >> 3) % O_span;
  const int cc = idx / (8 * O_span);
  const int od = o_base + ol;                // destination row
  short8 vh = {0,0,0,0,0,0,0,0}, vl = {0,0,0,0,0,0,0,0};
  if (ol < O) {
    const float* sp = src + (size_t)y * src_ls + (size_t)ol * ldsrc
                    + cc * 64 + ((qs ^ (od & 7)) << 3);
    const float4 a = *(const float4*)sp;
    const float4 c = *(const float4*)(sp + 4);
    float wv[8] = {a.x,a.y,a.z,a.w,c.x,c.y,c.z,c.w};
    #pragma unroll
    for (int j = 0; j < 8; ++j) {
      const unsigned short hh = f2bf(wv[j]);
      vh[j] = (short)hh;
      vl[j] = (short)f2bf(wv[j] - bfh(hh));
    }
  }
  const size_t d = ((size_t)cc * O_pad + od) * 64 + qs * 8;
  *(short8*)&dh[(size_t)y * dst_ls + d] = vh;
  *(short8*)&dl[(size_t)y * dst_ls + d] = vl;
}

// ---------------------------------------------------------------------------
// conv1: [128,3] x x[B,N,3] -> h0 nT hi/lo [B][N][128], bn+relu
__global__ __launch_bounds__(256) void k_conv1(
    const float* __restrict__ x, const float* __restrict__ w,
    const float* __restrict__ g, const float* __restrict__ bb,
    unsigned short* __restrict__ h0h, unsigned short* __restrict__ h0l)
{
  const int tid = threadIdx.x;
  const int n = blockIdx.x * 32 + (tid >> 3);
  const int oc = (tid & 7) * 16;
  const int b = blockIdx.y;
  const float x0 = x[((size_t)b * NP + n) * 3 + 0];
  const float x1 = x[((size_t)b * NP + n) * 3 + 1];
  const float x2 = x[((size_t)b * NP + n) * 3 + 2];
  const size_t base = ((size_t)b * NP + n) * 128 + oc;
  #pragma unroll
  for (int half = 0; half < 2; ++half) {
    short8 vh, vl;
    #pragma unroll
    for (int j = 0; j < 8; ++j) {
      const int o = oc + half * 8 + j;
      float v = w[o*3]*x0 + w[o*3+1]*x1 + w[o*3+2]*x2;
      v = v * (g[o] * rsqrtf(1.f + 1e-5f)) + bb[o];
      v = fmaxf(v, 0.f);
      const unsigned short hh = f2bf(v);
      vh[j] = (short)hh;
      vl[j] = (short)f2bf(v - bfh(hh));
    }
    *(short8*)&h0h[base + half * 8] = vh;
    *(short8*)&h0l[base + half * 8] = vl;
  }
}

// ---------------------------------------------------------------------------
// MFMA GEMM. Pre-split weights, XCD-aware swizzle, OT o x (NT*64) n tile.
// 4 waves n-split; W staging register-prefetched + double-buffered LDS, one
// barrier per chunk. APF: register-prefetch A. WLO: keep W lo-plane.
// AHI: read only the A hi-plane. OLO: write the nT lo-plane.
template<int ACT, bool BN, bool RES, bool CNBF, int OT, int NT,
         bool QV = false, bool APF = true, bool WLO = true, bool AHI = false,
         bool OLO = true>
__global__ __launch_bounds__(256) void k_mm(
    const unsigned short* __restrict__ Ah, const unsigned short* __restrict__ Al,
    int ldA, size_t A_bs,
    const unsigned short* __restrict__ Whp, const unsigned short* __restrict__ Wlp,
    int O_pad,
    const float* __restrict__ convb, int convb_bs,
    const float* __restrict__ bng, const float* __restrict__ bnb,
    const unsigned short* __restrict__ Rh, const unsigned short* __restrict__ Rl,
    int ldR, size_t R_bs,
    unsigned short* __restrict__ Onh, unsigned short* __restrict__ Onl,
    int ldON, size_t ON_bs,
    float* __restrict__ Ocn, size_t OCN_bs,
    int O, int Cin)
{
  constexpr int OF = OT / 16;
  constexpr int NTILES = NP / (NT * 64);
  constexpr int CHK = NTILES / 8;
  constexpr int STR = OF * 16 + 8;
  constexpr int LW_US = OT * 64;               // ushorts per W plane
  constexpr int ST_US = 64 * STR;
  constexpr int WBUF = WLO ? 4 * LW_US : 2 * LW_US;
  constexpr int SM_US = (WBUF > 2*ST_US) ? WBUF : 2*ST_US;
  constexpr int PW = OT / 32;                  // short8 per thread per plane

  const int bid = blockIdx.x;
  const int j  = bid >> 3;
  const int nt = (bid & 7) * CHK + (j % CHK);
  const int o0 = (j / CHK) * OT;
  const int n0 = nt * (NT * 64);
  const int b  = blockIdx.y;
  const int tid = threadIdx.x;
  const int w = tid >> 6, lane = tid & 63, lo = lane & 15, hi = lane >> 4;

  __shared__ __align__(16) unsigned short smem[SM_US];
  unsigned short* sTh = smem;                  // union: epilogue only
  unsigned short* sTl = smem + ST_US;

  const unsigned short* Ahb = Ah + (size_t)b * A_bs;
  const unsigned short* Alb = Al + (size_t)b * A_bs;

  f32x4 acc[NT][OF];
  #pragma unroll
  for (int nf = 0; nf < NT; ++nf)
    #pragma unroll
    for (int of = 0; of < OF; ++of) acc[nf][of] = (f32x4){0.f,0.f,0.f,0.f};

  const int nw = n0 + w * (NT * 16);

  short8 wrh[PW], wrl[PW];
  short8 a0h[2][NT], a0l[2][NT], a1h[2][NT], a1l[2][NT];

  auto loadW = [&](int ci) {
    const size_t wb = ((size_t)ci * O_pad + o0) * 64;
    #pragma unroll
    for (int q = 0; q < PW; ++q) {
      const int cid = tid + q * 256;
      wrh[q] = ld8(Whp + wb + (size_t)cid * 8);
      if constexpr (WLO) wrl[q] = ld8(Wlp + wb + (size_t)cid * 8);
    }
  };
  auto writeW = [&](unsigned short* bWh, unsigned short* bWl) {
    #pragma unroll
    for (int q = 0; q < PW; ++q) {
      const int cid = tid + q * 256;
      *(short8*)&bWh[cid * 8] = wrh[q];
      if constexpr (WLO) *(short8*)&bWl[cid * 8] = wrl[q];
    }
  };

#define LOAD_A(AH, AL, C0)                                             \
  { _Pragma("unroll")                                                  \
    for (int ks = 0; ks < 2; ++ks) {                                   \
      _Pragma("unroll")                                                \
      for (int nf = 0; nf < NT; ++nf) {                                \
        const int n = nw + nf * 16 + lo;                               \
        const size_t idx = (size_t)n * ldA + (C0) + ks * 32 + hi * 8;  \
        AH[ks][nf] = ld8(Ahb + idx);                                   \
        if constexpr (!AHI) AL[ks][nf] = ld8(Alb + idx);               \
      }                                                                \
    } }

#define COMPUTE(BWH, BWL, AHc, ALc)                                    \
  { _Pragma("unroll")                                                  \
    for (int ks = 0; ks < 2; ++ks) {                                   \
      _Pragma("unroll")                                                \
      for (int of = 0; of < OF; ++of) {                                \
        const int row = of * 16 + lo;                                  \
        const int qs = (ks * 4 + hi) ^ (row & 7);                      \
        const short8 bh = ld8(&(BWH)[row * 64 + qs * 8]);              \
        _Pragma("unroll")                                              \
        for (int nf = 0; nf < NT; ++nf)                                \
          acc[nf][of] = MFMA_BF16(AHc[ks][nf], bh, acc[nf][of], 0,0,0);\
        if constexpr (WLO) {                                           \
          const short8 bl = ld8(&(BWL)[row * 64 + qs * 8]);            \
          _Pragma("unroll")                                            \
          for (int nf = 0; nf < NT; ++nf)                              \
            acc[nf][of] = MFMA_BF16(AHc[ks][nf], bl, acc[nf][of],0,0,0);\
        }                                                              \
        if constexpr (!AHI) {                                          \
          _Pragma("unroll")                                            \
          for (int nf = 0; nf < NT; ++nf)                              \
            acc[nf][of] = MFMA_BF16(ALc[ks][nf], bh, acc[nf][of],0,0,0);\
        }                                                              \
      }                                                                \
    } }

  // preload chunk 0
  loadW(0);
  if constexpr (APF) { LOAD_A(a0h, a0l, 0); }

  const int nch = Cin >> 6;                    // even by construction
  for (int cc = 0; cc < nch; cc += 2) {
    // even chunk -> LDS buffer 0
    {
      unsigned short* bWh = smem;
      unsigned short* bWl = WLO ? smem + LW_US : smem;
      writeW(bWh, bWl);
      loadW(cc + 1);                           // always valid (nch even)
      if constexpr (APF) { LOAD_A(a1h, a1l, (cc + 1) * 64); }
      __syncthreads();
      if constexpr (!APF) { LOAD_A(a0h, a0l, cc * 64); }
      COMPUTE(bWh, bWl, a0h, a0l);
    }
    // odd chunk -> LDS buffer 1
    {
      unsigned short* bWh = smem + (WLO ? 2 * LW_US : LW_US);
      unsigned short* bWl = WLO ? bWh + LW_US : bWh;
      writeW(bWh, bWl);
      if (cc + 2 < nch) {
        loadW(cc + 2);
        if constexpr (APF) { LOAD_A(a0h, a0l, (cc + 2) * 64); }
      }
      __syncthreads();
      if constexpr (!APF) { LOAD_A(a1h, a1l, (cc + 1) * 64); }
      COMPUTE(bWh, bWl, a1h, a1l);
    }
  }
#undef LOAD_A
#undef COMPUTE

  // ---- CN outputs: packed r-quad stores, no LDS
  if (Ocn && (!QV || o0 >= 32)) {
    #pragma unroll
    for (int of = 0; of < OF; ++of) {
      const int o = o0 + of * 16 + lo;
      if (o < O) {
        const int oe = QV ? (o - 32) : o;
        const float cb = convb ? convb[(size_t)b * convb_bs + oe] : 0.f;
        float sg = 0.f, sb = 0.f;
        if (BN) { sg = bng[oe] * rsqrtf(1.f + 1e-5f); sb = bnb[oe]; }
        #pragma unroll
        for (int nf = 0; nf < NT; ++nf) {
          const int n = nw + nf * 16 + hi * 4;
          float vv[4];
          #pragma unroll
          for (int r = 0; r < 4; ++r) {
            float v = acc[nf][of][r] + cb;
            if (BN) v = v * sg + sb;
            if (ACT == 1) v = fmaxf(v, 0.f);
            if (ACT == 2) v = v > 0.f ? v : 0.2f * v;
            vv[r] = v;
          }
          if (CNBF) {
            ushort4 pk;
            pk.x = f2bf(vv[0]); pk.y = f2bf(vv[1]);
            pk.z = f2bf(vv[2]); pk.w = f2bf(vv[3]);
            *(ushort4*)&((unsigned short*)Ocn)[(size_t)b * OCN_bs + (size_t)oe * NP + n] = pk;
          } else {
            *(float4*)&Ocn[(size_t)b * OCN_bs + (size_t)oe * NP + n] =
                make_float4(vv[0], vv[1], vv[2], vv[3]);
          }
        }
      }
    }
  }

  // ---- nT outputs: LDS transpose per nf-round, 16B-coalesced stores
  if (Onh && (!QV || o0 == 0)) {
    #pragma unroll
    for (int nf = 0; nf < NT; ++nf) {
      __syncthreads();
      #pragma unroll
      for (int of = 0; of < OF; ++of) {
        const int o = o0 + of * 16 + lo;
        const float cb = (convb && !QV) ? convb[(size_t)b * convb_bs + o] : 0.f;
        float sg = 0.f, sb = 0.f;
        if (BN) { sg = bng[o] * rsqrtf(1.f + 1e-5f); sb = bnb[o]; }
        #pragma unroll
        for (int r = 0; r < 4; ++r) {
          float v = acc[nf][of][r] + cb;
          if (BN) v = v * sg + sb;
          if (ACT == 1) v = fmaxf(v, 0.f);
          if (ACT == 2) v = v > 0.f ? v : 0.2f * v;
          const int lrow = w * 16 + hi * 4 + r;
          const unsigned short hh = f2bf(v);
          sTh[lrow * STR + of * 16 + lo] = hh;
          if constexpr (OLO) sTl[lrow * STR + of * 16 + lo] = f2bf(v - bfh(hh));
        }
      }
      __syncthreads();
      for (int c = tid; c < 64 * OF * 2; c += 256) {
        const int lrow = c / (OF * 2);
        const int oc = (c % (OF * 2)) * 8;
        const int n = n0 + (lrow >> 4) * (NT * 16) + nf * 16 + (lrow & 15);
        const int o = o0 + oc;
        short8 hv = *(short8*)&sTh[lrow * STR + oc];
        short8 lv;
        if constexpr (OLO) lv = *(short8*)&sTl[lrow * STR + oc];
        if (RES) {
          const short8 rhv = ld8(Rh + (size_t)b * R_bs + (size_t)n * ldR + o);
          const short8 rlv = ld8(Rl + (size_t)b * R_bs + (size_t)n * ldR + o);
          #pragma unroll
          for (int jj = 0; jj < 8; ++jj) {
            float v = bf2f((unsigned short)hv[jj], (unsigned short)lv[jj])
                    + bf2f((unsigned short)rhv[jj], (unsigned short)rlv[jj]);
            const unsigned short hh2 = f2bf(v);
            hv[jj] = (short)hh2;
            lv[jj] = (short)f2bf(v - bfh(hh2));
          }
        }
        *(short8*)&Onh[(size_t)b * ON_bs + (size_t)n * ldON + o] = hv;
        if constexpr (OLO)
          *(short8*)&Onl[(size_t)b * ON_bs + (size_t)n * ldON + o] = lv;
      }
    }
  }
}

// ---------------------------------------------------------------------------
// pass A (MFMA): column stats of symmetric E = Q^T Q.
__global__ __launch_bounds__(256) void k_passA(
    const unsigned short* __restrict__ qh, const unsigned short* __restrict__ ql,
    float* __restrict__ pmax, float* __restrict__ psum)
{
  const int m0 = blockIdx.x * 64;
  const int ns = blockIdx.y;
  const int b  = blockIdx.z;
  const int tid = threadIdx.x;
  const int w = tid >> 6, lane = tid & 63, lo = lane & 15, hi = lane >> 4;
  const unsigned short* qhb = qh + (size_t)b * NP * 32;
  const unsigned short* qlb = ql + (size_t)b * NP * 32;

  short8 bh[4], bl[4];
  #pragma unroll
  for (int fj = 0; fj < 4; ++fj) {
    const int m = m0 + fj * 16 + lo;
    bh[fj] = ld8(qhb + (size_t)m * 32 + hi * 8);
    bl[fj] = ld8(qlb + (size_t)m * 32 + hi * 8);
  }
  float mx[4], sm[4];
  #pragma unroll
  for (int fj = 0; fj < 4; ++fj) { mx[fj] = -3e38f; sm[fj] = 0.f; }

  const int nbeg = ns * 512;
  for (int ch = 0; ch < 8; ++ch) {
    const int n0 = nbeg + ch * 64;
    const int nr = n0 + w * 16 + lo;
    const short8 ah = ld8(qhb + (size_t)nr * 32 + hi * 8);
    const short8 al = ld8(qlb + (size_t)nr * 32 + hi * 8);
    #pragma unroll
    for (int fj = 0; fj < 4; ++fj) {
      f32x4 e = MFMA_BF16(ah, bh[fj], (f32x4){0.f,0.f,0.f,0.f}, 0, 0, 0);
      e = MFMA_BF16(ah, bl[fj], e, 0, 0, 0);
      e = MFMA_BF16(al, bh[fj], e, 0, 0, 0);
      const float lm = fmaxf(fmaxf(e[0], e[1]), fmaxf(e[2], e[3]));
      const float nm = fmaxf(mx[fj], lm);
      sm[fj] = sm[fj] * __expf(mx[fj] - nm)
             + __expf(e[0]-nm) + __expf(e[1]-nm) + __expf(e[2]-nm) + __expf(e[3]-nm);
      mx[fj] = nm;
    }
  }
  #pragma unroll
  for (int fj = 0; fj < 4; ++fj) {
    #pragma unroll
    for (int off = 16; off <= 32; off <<= 1) {
      const float om = __shfl_down(mx[fj], off, 64);
      const float os = __shfl_down(sm[fj], off, 64);
      const float nm = fmaxf(mx[fj], om);
      sm[fj] = sm[fj] * __expf(mx[fj] - nm) + os * __expf(om - nm);
      mx[fj] = nm;
    }
  }
  __shared__ float wmx[4][64], wsm[4][64];
  if (hi == 0) {
    #pragma unroll
    for (int fj = 0; fj < 4; ++fj) {
      wmx[w][fj * 16 + lo] = mx[fj];
      wsm[w][fj * 16 + lo] = sm[fj];
    }
  }
  __syncthreads();
  if (tid < 64) {
    float fm = wmx[0][tid], fs = wsm[0][tid];
    #pragma unroll
    for (int w2 = 1; w2 < 4; ++w2) {
      const float om = wmx[w2][tid], os = wsm[w2][tid];
      const float nm = fmaxf(fm, om);
      fs = fs * __expf(fm - nm) + os * __expf(om - nm);
      fm = nm;
    }
    pmax[((size_t)b * 8 + ns) * NP + m0 + tid] = fm;
    psum[((size_t)b * 8 + ns) * NP + m0 + tid] = fs;
  }
}

// ---------------------------------------------------------------------------
// pass B (MFMA): combineA inlined; 8-way n-split; bf16 ypart; qT fragment
// loads software-pipelined one chunk ahead (named A0/A1 register sets).
__global__ __launch_bounds__(256) void k_passB(
    const unsigned short* __restrict__ qh, const unsigned short* __restrict__ ql,
    const unsigned short* __restrict__ vbf,
    const float* __restrict__ pmax, const float* __restrict__ psum,
    unsigned short* __restrict__ ypart, float* __restrict__ csp)
{
  const int m0 = blockIdx.x * 64;
  const int ns = blockIdx.y;            // 0..7
  const int b  = blockIdx.z;
  const int tid = threadIdx.x;
  const int w = tid >> 6, lane = tid & 63, lo = lane & 15, hi = lane >> 4;
  const unsigned short* qhb = qh + (size_t)b * NP * 32;
  const unsigned short* qlb = ql + (size_t)b * NP * 32;
  const unsigned short* vbb = vbf + (size_t)b * 128 * NP;

  __shared__ __align__(16) unsigned short Pt[2][64 * 64];
  __shared__ float csred[4][64];
  __shared__ float rm_l[512], ri_l[512];

  const int nbeg = ns * 512;
  {
    const int n2 = tid * 2;
    #pragma unroll
    for (int k = 0; k < 2; ++k) {
      const int n = nbeg + n2 + k;
      float mx = -3e38f;
      #pragma unroll
      for (int s = 0; s < 8; ++s)
        mx = fmaxf(mx, pmax[((size_t)b*8 + s) * NP + n]);
      float sm = 0.f;
      #pragma unroll
      for (int s = 0; s < 8; ++s)
        sm += psum[((size_t)b*8 + s) * NP + n] * __expf(pmax[((size_t)b*8 + s) * NP + n] - mx);
      rm_l[n2 + k] = mx;
      ri_l[n2 + k] = 1.f / sm;
    }
  }

  short8 bh[4], bl[4];
  #pragma unroll
  for (int fj = 0; fj < 4; ++fj) {
    const int m = m0 + fj * 16 + lo;
    bh[fj] = ld8(qhb + (size_t)m * 32 + hi * 8);
    bl[fj] = ld8(qlb + (size_t)m * 32 + hi * 8);
  }
  f32x4 yacc[2][4];
  #pragma unroll
  for (int cf = 0; cf < 2; ++cf)
    #pragma unroll
    for (int fj = 0; fj < 4; ++fj) yacc[cf][fj] = (f32x4){0.f,0.f,0.f,0.f};
  float cs[4] = {0.f, 0.f, 0.f, 0.f};

  const int swz = (lo & 7) << 3;
  const int c0 = w * 32;
  const int nrow = w * 16 + lo;          // wave-local n row within chunk

#define PB_CHUNK(CH, AH, AL, NAH, NAL, PRELOAD)                          \
  {                                                                      \
    unsigned short* Ptc = &Pt[(CH) & 1][0];                              \
    const int n0 = nbeg + (CH) * 64;                                     \
    f32x4 e[4];                                                          \
    _Pragma("unroll")                                                    \
    for (int fj = 0; fj < 4; ++fj) {                                     \
      e[fj] = MFMA_BF16(AH, bh[fj], (f32x4){0.f,0.f,0.f,0.f}, 0, 0, 0);  \
      e[fj] = MFMA_BF16(AH, bl[fj], e[fj], 0, 0, 0);                     \
      e[fj] = MFMA_BF16(AL, bh[fj], e[fj], 0, 0, 0);                     \
    }                                                                    \
    if (PRELOAD) {                                                       \
      const int nr2 = nbeg + ((CH) + 1) * 64 + nrow;                     \
      NAH = ld8(qhb + (size_t)nr2 * 32 + hi * 8);                        \
      NAL = ld8(qlb + (size_t)nr2 * 32 + hi * 8);                        \
    }                                                                    \
    float rmv[4], riv[4];                                                \
    _Pragma("unroll")                                                    \
    for (int r = 0; r < 4; ++r) {                                        \
      const int nl = (CH) * 64 + w * 16 + hi * 4 + r;                    \
      rmv[r] = rm_l[nl];                                                 \
      riv[r] = ri_l[nl];                                                 \
    }                                                                    \
    _Pragma("unroll")                                                    \
    for (int fj = 0; fj < 4; ++fj) {                                     \
      float p[4];                                                        \
      _Pragma("unroll")                                                  \
      for (int r = 0; r < 4; ++r) p[r] = __expf(e[fj][r] - rmv[r]) * riv[r]; \
      cs[fj] += p[0] + p[1] + p[2] + p[3];                               \
      ushort4 pk;                                                        \
      pk.x = f2bf(p[0]); pk.y = f2bf(p[1]);                              \
      pk.z = f2bf(p[2]); pk.w = f2bf(p[3]);                              \
      const int row = fj * 16 + lo;                                      \
      const int col = (w * 16 + hi * 4) ^ swz;                           \
      *(ushort4*)&Ptc[row * 64 + col] = pk;                              \
    }                                                                    \
    short8 vfrag[2][2];                                                  \
    _Pragma("unroll")                                                    \
    for (int cf = 0; cf < 2; ++cf)                                       \
      _Pragma("unroll")                                                  \
      for (int ks = 0; ks < 2; ++ks)                                     \
        vfrag[cf][ks] = ld8(vbb + (size_t)(c0 + cf*16 + lo) * NP + n0 + ks*32 + hi*8); \
    __syncthreads();                                                     \
    _Pragma("unroll")                                                    \
    for (int ks = 0; ks < 2; ++ks) {                                     \
      _Pragma("unroll")                                                  \
      for (int fj = 0; fj < 4; ++fj) {                                   \
        const int row = fj * 16 + lo;                                    \
        const int col = (ks * 32 + hi * 8) ^ swz;                        \
        const short8 pf = ld8(&Ptc[row * 64 + col]);                     \
        _Pragma("unroll")                                                \
        for (int cf = 0; cf < 2; ++cf)                                   \
          yacc[cf][fj] = MFMA_BF16(vfrag[cf][ks], pf, yacc[cf][fj], 0, 0, 0); \
      }                                                                  \
    }                                                                    \
  }

  // preload chunk 0 qT fragments
  short8 pa_h, pa_l, pb_h, pb_l;
  {
    const int nr = nbeg + nrow;
    pa_h = ld8(qhb + (size_t)nr * 32 + hi * 8);
    pa_l = ld8(qlb + (size_t)nr * 32 + hi * 8);
  }
  __syncthreads();   // rm_l/ri_l ready (also covered by chunk barriers below)

  #pragma unroll
  for (int cp = 0; cp < 4; ++cp) {
    const int ch0 = cp * 2;
    PB_CHUNK(ch0,     pa_h, pa_l, pb_h, pb_l, true);
    PB_CHUNK(ch0 + 1, pb_h, pb_l, pa_h, pa_l, (ch0 + 2 < 8));
  }
#undef PB_CHUNK

  // ---- write Y partials as bf16 (halved traffic)
  unsigned short* yp = ypart + ((size_t)b * 8 + ns) * NP * 128;
  #pragma unroll
  for (int cf = 0; cf < 2; ++cf)
    #pragma unroll
    for (int fj = 0; fj < 4; ++fj) {
      const int m = m0 + fj * 16 + lo;
      const int c = w * 32 + cf * 16 + hi * 4;
      ushort4 pk;
      pk.x = f2bf(yacc[cf][fj][0]); pk.y = f2bf(yacc[cf][fj][1]);
      pk.z = f2bf(yacc[cf][fj][2]); pk.w = f2bf(yacc[cf][fj][3]);
      *(ushort4*)&yp[(size_t)m * 128 + c] = pk;
    }
  #pragma unroll
  for (int fj = 0; fj < 4; ++fj) {
    cs[fj] += __shfl_down(cs[fj], 16, 64);
    cs[fj] += __shfl_down(cs[fj], 32, 64);
  }
  __syncthreads();
  if (hi == 0) {
    #pragma unroll
    for (int fj = 0; fj < 4; ++fj) csred[w][fj * 16 + lo] = cs[fj];
  }
  __syncthreads();
  if (tid < 64)
    csp[((size_t)b * 8 + ns) * NP + m0 + tid] =
        csred[0][tid] + csred[1][tid] + csred[2][tid] + csred[3][tid];
}

// combineB: d = h - (sum_ns y)/(1e-9 + sum_ns cs), emitted as nT hi/lo [N][128]
__global__ __launch_bounds__(256) void k_combineB(
    const unsigned short* __restrict__ ypart, const float* __restrict__ csp,
    const unsigned short* __restrict__ hinh, const unsigned short* __restrict__ hinl,
    int ldH, size_t H_bs,
    unsigned short* __restrict__ dh, unsigned short* __restrict__ dl)
{
  const size_t i = (size_t)blockIdx.x * 256 + threadIdx.x;  // < B*NP*128
  const int c = (int)(i & 127);
  const int n = (int)((i >> 7) & (NP - 1));
  const int b = (int)(i >> 19);
  float s = 1e-9f, y = 0.f;
  #pragma unroll
  for (int ns = 0; ns < 8; ++ns) {
    y += bfh(ypart[(((size_t)b*8 + ns) * NP + n) * 128 + c]);
    s += csp[((size_t)b*8 + ns) * NP + n];
  }
  const float h = bf2f(hinh[(size_t)b * H_bs + (size_t)n * ldH + c],
                       hinl[(size_t)b * H_bs + (size_t)n * ldH + c]);
  const float d = h - y / s;
  const unsigned short hh = f2bf(d);
  dh[i] = hh;
  dl[i] = f2bf(d - bfh(hh));
}

// ---------------------------------------------------------------------------
// per-channel max/mean of fuse output, hi-plane-only nT [N][1024].
__global__ __launch_bounds__(256) void k_maxavg_p(
    const unsigned short* __restrict__ fh,
    float* __restrict__ pmx, float* __restrict__ psm)
{
  const int tid = threadIdx.x;
  const int c4 = (tid & 15) * 4;
  const int st = tid >> 4;
  const int o0 = blockIdx.x * 64;
  const int nsp = blockIdx.y;
  const int b = blockIdx.z;
  const int nbeg = nsp * 256;
  const unsigned short* fhb = fh + (size_t)b * NP * 1024 + o0 + c4;
  float mx[4] = {-3e38f,-3e38f,-3e38f,-3e38f}, sm[4] = {0.f,0.f,0.f,0.f};
  #pragma unroll 4
  for (int n = nbeg + st; n < nbeg + 256; n += 16) {
    const ushort4 vh = *(const ushort4*)(fhb + (size_t)n * 1024);
    const float v0 = bfh(vh.x), v1 = bfh(vh.y);
    const float v2 = bfh(vh.z), v3 = bfh(vh.w);
    mx[0] = fmaxf(mx[0], v0); sm[0] += v0;
    mx[1] = fmaxf(mx[1], v1); sm[1] += v1;
    mx[2] = fmaxf(mx[2], v2); sm[2] += v2;
    mx[3] = fmaxf(mx[3], v3); sm[3] += v3;
  }
  __shared__ float smx[16][64], ssm[16][64];
  #pragma unroll
  for (int j = 0; j < 4; ++j) { smx[st][c4 + j] = mx[j]; ssm[st][c4 + j] = sm[j]; }
  __syncthreads();
  if (tid < 64) {
    float m = -3e38f, s = 0.f;
    #pragma unroll
    for (int k = 0; k < 16; ++k) { m = fmaxf(m, smx[k][tid]); s += ssm[k][tid]; }
    pmx[((size_t)b * 16 + nsp) * 1024 + o0 + tid] = m;
    psm[((size_t)b * 16 + nsp) * 1024 + o0 + tid] = s;
  }
}

__global__ __launch_bounds__(256) void k_maxavg_c(
    const float* __restrict__ pmx, const float* __restrict__ psm,
    float* __restrict__ xm, float* __restrict__ xa)
{
  const int i = blockIdx.x * 256 + threadIdx.x;   // < B*1024
  const int c = i & 1023;
  const int b = i >> 10;
  float m = -3e38f, s = 0.f;
  #pragma unroll
  for (int k = 0; k < 16; ++k) {
    m = fmaxf(m, pmx[((size_t)b * 16 + k) * 1024 + c]);
    s += psm[((size_t)b * 16 + k) * 1024 + c];
  }
  xm[i] = m;
  xa[i] = s * (1.f / NP);
}

__global__ void k_cls(const float* __restrict__ cl, const float* __restrict__ W,
                      const float* __restrict__ g, const float* __restrict__ bb,
                      float* __restrict__ clsf)
{
  const int t = threadIdx.x;
  const int b = t >> 6, o = t & 63;
  float a = 0.f;
  #pragma unroll
  for (int j = 0; j < 16; ++j) a += W[o * 16 + j] * cl[b * 16 + j];
  a = a * (g[o] * rsqrtf(1.f + 1e-5f)) + bb[o];
  clsf[b * 64 + o] = a > 0.f ? a : 0.2f * a;
}

__global__ __launch_bounds__(256) void k_gbias(
    const float* __restrict__ W1, const float* __restrict__ xm,
    const float* __restrict__ xa, const float* __restrict__ clsf,
    const float* __restrict__ c1b, float* __restrict__ gb)
{
  const int o = blockIdx.x, b = blockIdx.y;
  float a = 0.f;
  for (int j = threadIdx.x; j < 2112; j += 256) {
    const float gv = (j < 1024) ? xm[b * 1024 + j]
                   : (j < 2048) ? xa[b * 1024 + (j - 1024)]
                                : clsf[b * 64 + (j - 2048)];
    a += W1[(size_t)o * 3136 + 1024 + j] * gv;
  }
  a = wsum(a);
  __shared__ float red[4];
  const int w = threadIdx.x >> 6;
  if ((threadIdx.x & 63) == 0) red[w] = a;
  __syncthreads();
  if (threadIdx.x == 0) gb[b * 512 + o] = red[0] + red[1] + red[2] + red[3] + c1b[o];
}

// ---------------------------------------------------------------------------
extern "C" void kernel_launch(void* const* d_in, const int* in_sizes, int n_in,
                              void* d_out, int out_size, void* d_ws, size_t ws_size,
                              hipStream_t stream)
{
  const float* x        = (const float*)d_in[0];
  const float* cls_lab  = (const float*)d_in[1];
  const float* conv1_w  = (const float*)d_in[2];
  const float* bn1_g    = (const float*)d_in[3];
  const float* bn1_b    = (const float*)d_in[4];
  const float* conv2_w  = (const float*)d_in[5];
  const float* bn2_g    = (const float*)d_in[6];
  const float* bn2_b    = (const float*)d_in[7];
  const float* sa_qk_w  = (const float*)d_in[8];
  const float* sa_v_w   = (const float*)d_in[9];
  const float* sa_v_b   = (const float*)d_in[10];
  const float* sa_t_w   = (const float*)d_in[11];
  const float* sa_t_b   = (const float*)d_in[12];
  const float* sa_bn_g  = (const float*)d_in[13];
  const float* sa_bn_b  = (const float*)d_in[14];
  const float* fuse_w   = (const float*)d_in[15];
  const float* fuse_g   = (const float*)d_in[16];
  const float* fuse_b   = (const float*)d_in[17];
  const float* label_w  = (const float*)d_in[18];
  const float* label_g  = (const float*)d_in[19];
  const float* label_b  = (const float*)d_in[20];
  const float* c1_w     = (const float*)d_in[21];
  const float* c1_b     = (const float*)d_in[22];
  const float* bns1_g   = (const float*)d_in[23];
  const float* bns1_b   = (const float*)d_in[24];
  const float* c2_w     = (const float*)d_in[25];
  const float* c2_b     = (const float*)d_in[26];
  const float* bns2_g   = (const float*)d_in[27];
  const float* bns2_b   = (const float*)d_in[28];
  const float* c3_w     = (const float*)d_in[29];
  const float* c3_b     = (const float*)d_in[30];
  float* outp = (float*)d_out;

  float* f = (float*)d_ws;
  size_t off = 0;
  auto us = [&](size_t n_ushort) { unsigned short* p = (unsigned short*)(f + off);
                                   off += (n_ushort + 1) / 2; return p; };
  unsigned short* h0h  = us((size_t)BB*NP*128);
  unsigned short* h0l  = us((size_t)BB*NP*128);
  unsigned short* h1h  = us((size_t)BB*NP*128);
  unsigned short* h1l  = us((size_t)BB*NP*128);
  unsigned short* hch  = us((size_t)BB*NP*512);
  unsigned short* hcl  = us((size_t)BB*NP*512);
  unsigned short* qTh  = us((size_t)BB*NP*32);
  unsigned short* qTl  = us((size_t)BB*NP*32);
  unsigned short* vb   = us((size_t)BB*128*NP);
  unsigned short* dhb  = us((size_t)BB*NP*128);
  unsigned short* dlb  = us((size_t)BB*NP*128);
  // pre-split weight buffers (persist across whole call)
  unsigned short* wc2h = us(2*128*64);        unsigned short* wc2l = us(2*128*64);
  unsigned short* wqvh = us(4*2*160*64);      unsigned short* wqvl = us(4*2*160*64);
  unsigned short* wth  = us(4*2*128*64);      unsigned short* wtl  = us(4*2*128*64);
  unsigned short* wfh  = us(8*1024*64);       unsigned short* wfl  = us(8*1024*64);
  unsigned short* w1h  = us(16*512*64);       unsigned short* w1l  = us(16*512*64);
  unsigned short* w2h  = us(8*256*64);        unsigned short* w2l  = us(8*256*64);
  unsigned short* w3h  = us(4*64*64);         unsigned short* w3l  = us(4*64*64);
  float* pmax  = f + off; off += (size_t)BB*8*NP;
  float* psum  = f + off; off += (size_t)BB*8*NP;
  float* csp   = f + off; off += (size_t)BB*8*NP;
  float* pmx   = f + off; off += (size_t)BB*16*1024;
  float* psm   = f + off; off += (size_t)BB*16*1024;
  float* xm    = f + off; off += (size_t)BB*1024;
  float* xa    = f + off; off += (size_t)BB*1024;
  float* clsf  = f + off; off += (size_t)BB*64;
  float* gb    = f + off; off += (size_t)BB*512;
  off = (off + 255) & ~(size_t)255;
  unsigned short* ypart = (unsigned short*)(f + off);   // BB*8*NP*128 ushorts
  unsigned short* fuh = ypart;                          // alias (disjoint in time)
  unsigned short* o1h = fuh + (size_t)BB*NP*1024;
  unsigned short* o2h = o1h + (size_t)BB*NP*512;

  const dim3 blk(256);

  // ---- weight pre-split (LDS-ready layout)
  k_wsplit<<<dim3(8,1),   blk, 0, stream>>>(conv2_w, 0, wc2h, wc2l, 0, 128, 128, 128, 0, 128, 128);
  k_wsplit<<<dim3(2,4),   blk, 0, stream>>>(sa_qk_w, 32*128, wqvh, wqvl, 2*160*64, 32, 32, 160, 0, 128, 128);
  k_wsplit<<<dim3(8,4),   blk, 0, stream>>>(sa_v_w, 128*128, wqvh, wqvl, 2*160*64, 128, 128, 160, 32, 128, 128);
  k_wsplit<<<dim3(8,4),   blk, 0, stream>>>(sa_t_w, 128*128, wth, wtl, 2*128*64, 128, 128, 128, 0, 128, 128);
  k_wsplit<<<dim3(256,1), blk, 0, stream>>>(fuse_w, 0, wfh, wfl, 0, 1024, 1024, 1024, 0, 512, 512);
  k_wsplit<<<dim3(256,1), blk, 0, stream>>>(c1_w, 0, w1h, w1l, 0, 512, 512, 512, 0, 1024, 3136);
  k_wsplit<<<dim3(64,1),  blk, 0, stream>>>(c2_w, 0, w2h, w2l, 0, 256, 256, 256, 0, 512, 512);
  k_wsplit<<<dim3(8,1),   blk, 0, stream>>>(c3_w, 0, w3h, w3l, 0, 50, 64, 64, 0, 256, 256);

  k_conv1<<<dim3(128, BB), blk, 0, stream>>>(x, conv1_w, bn1_g, bn1_b, h0h, h0l);

  // conv2: 128<-128, bn+relu -> h1 nT  (full precision)
  k_mm<1,true,false,false,32,1><<<dim3(256,BB), blk, 0, stream>>>(
      h0h, h0l, 128, (size_t)NP*128, wc2h, wc2l, 128, nullptr, 0, bn2_g, bn2_b,
      nullptr, nullptr, 0, 0, h1h, h1l, 128, (size_t)NP*128, nullptr, 0, 128, 128);

  for (int i = 0; i < 4; ++i) {
    const unsigned short* hinh = (i == 0) ? h1h : hch + (size_t)(i-1)*128;
    const unsigned short* hinl = (i == 0) ? h1l : hcl + (size_t)(i-1)*128;
    const int ldH = (i == 0) ? 128 : 512;
    const size_t H_bs = (size_t)NP * ldH;

    // fused q+v: O=160 stacked; q rows -> qT nT, v rows -> bf16 CN + bias
    k_mm<0,false,false,true,32,1,true><<<dim3(320,BB), blk, 0, stream>>>(
        hinh, hinl, ldH, H_bs, wqvh + (size_t)i*2*160*64, wqvl + (size_t)i*2*160*64, 160,
        sa_v_b + (size_t)i*128, 0, nullptr, nullptr,
        nullptr, nullptr, 0, 0,
        qTh, qTl, 32, (size_t)NP*32,
        (float*)vb, (size_t)128*NP, 160, 128);

    k_passA<<<dim3(64,8,BB), blk, 0, stream>>>(qTh, qTl, pmax, psum);
    k_passB<<<dim3(64,8,BB), blk, 0, stream>>>(qTh, qTl, vb, pmax, psum, ypart, csp);
    k_combineB<<<dim3(BB*NP*128/256), blk, 0, stream>>>(
        ypart, csp, hinh, hinl, ldH, H_bs, dhb, dlb);

    // t: 128<-128 on (h - x_r), + t_b, bn, relu, + residual h  (W-hi only)
    k_mm<1,true,true,false,32,1,false,true,false><<<dim3(256,BB), blk, 0, stream>>>(
        dhb, dlb, 128, (size_t)NP*128, wth + (size_t)i*2*128*64, wtl + (size_t)i*2*128*64, 128,
        sa_t_b + (size_t)i*128, 0, sa_bn_g + (size_t)i*128, sa_bn_b + (size_t)i*128,
        hinh, hinl, ldH, H_bs,
        hch + (size_t)i*128, hcl + (size_t)i*128, 512, (size_t)NP*512,
        nullptr, 0, 128, 128);
  }

  // fuse: 1024<-512, bn + leaky -> fuse nT hi only (pure-bf16 tail)
  k_mm<2,true,false,false,64,2,false,true,false,true,false><<<dim3(512,BB), blk, 0, stream>>>(
      hch, hcl, 512, (size_t)NP*512, wfh, wfl, 1024, nullptr, 0, fuse_g, fuse_b,
      nullptr, nullptr, 0, 0, fuh, nullptr, 1024, (size_t)NP*1024, nullptr, 0, 1024, 512);

  k_maxavg_p<<<dim3(16,16,BB), blk, 0, stream>>>(fuh, pmx, psm);
  k_maxavg_c<<<dim3(BB*1024/256), blk, 0, stream>>>(pmx, psm, xm, xa);
  k_cls<<<dim3(1), dim3(128), 0, stream>>>(cls_lab, label_w, label_g, label_b, clsf);
  k_gbias<<<dim3(512, BB), blk, 0, stream>>>(c1_w, xm, xa, clsf, c1_b, gb);

  // convs1: 512<-1024 (+gb), bn, relu -> out1 hi only (pure-bf16)
  k_mm<1,true,false,false,64,2,false,true,false,true,false><<<dim3(256,BB), blk, 0, stream>>>(
      fuh, fuh, 1024, (size_t)NP*1024, w1h, w1l, 512, gb, 512, bns1_g, bns1_b,
      nullptr, nullptr, 0, 0, o1h, nullptr, 512, (size_t)NP*512, nullptr, 0, 512, 1024);

  // convs2: 256<-512 + c2_b, bn, relu -> out2 hi only (pure-bf16)
  k_mm<1,true,false,false,64,1,false,true,false,true,false><<<dim3(256,BB), blk, 0, stream>>>(
      o1h, o1h, 512, (size_t)NP*512, w2h, w2l, 256, c2_b, 0, bns2_g, bns2_b,
      nullptr, nullptr, 0, 0, o2h, nullptr, 256, (size_t)NP*256, nullptr, 0, 256, 512);

  // convs3: 50<-256 + c3_b -> fp32 [50][N] output (pure-bf16 inputs)
  k_mm<0,false,false,false,64,1,false,true,false,true><<<dim3(64,BB), blk, 0, stream>>>(
      o2h, o2h, 256, (size_t)NP*256, w3h, w3l, 64, c3_b, 0, nullptr, nullptr,
      nullptr, nullptr, 0, 0, nullptr, nullptr, 0, 0,
      outp, (size_t)50*NP, 50, 256);
}

// Round 23
// 350.566 us; speedup vs baseline: 1.0829x; 1.0829x over previous
//
#include <hip/hip_runtime.h>

#define NP 4096
#define BB 2

typedef __attribute__((ext_vector_type(8))) short short8;
typedef __attribute__((ext_vector_type(4))) float f32x4;
#define MFMA_BF16 __builtin_amdgcn_mfma_f32_16x16x32_bf16

__device__ __forceinline__ float wsum(float v){
  #pragma unroll
  for (int o = 32; o; o >>= 1) v += __shfl_down(v, o, 64);
  return v;
}
__device__ __forceinline__ unsigned short f2bf(float x){
  unsigned int u = __float_as_uint(x);
  return (unsigned short)((u + 0x7fffu + ((u >> 16) & 1u)) >> 16);
}
__device__ __forceinline__ float bfh(unsigned short h){
  return __uint_as_float((unsigned int)h << 16);
}
__device__ __forceinline__ float bf2f(unsigned short h, unsigned short l){
  return bfh(h) + bfh(l);
}
__device__ __forceinline__ short8 ld8(const unsigned short* p){
  return *(const short8*)p;
}

// ---------------------------------------------------------------------------
// Pre-split fp32 weights -> bf16 hi/lo, LDS-ready layout, row-range variant.
__global__ __launch_bounds__(256) void k_wsplit(
    const float* __restrict__ src, size_t src_ls,
    unsigned short* __restrict__ dh, unsigned short* __restrict__ dl,
    size_t dst_ls, int O, int O_span, int O_pad, int o_base, int Cin, int ldsrc)
{
  const int y = blockIdx.y;
  const int idx = blockIdx.x * 256 + threadIdx.x;
  const int chunks = (Cin >> 6) * O_span * 8;
  if (idx >= chunks) return;
  const int qs = idx & 7;
  const int ol = (idx >> 3) % O_span;
  const int cc = idx / (8 * O_span);
  const int od = o_base + ol;                // destination row
  short8 vh = {0,0,0,0,0,0,0,0}, vl = {0,0,0,0,0,0,0,0};
  if (ol < O) {
    const float* sp = src + (size_t)y * src_ls + (size_t)ol * ldsrc
                    + cc * 64 + ((qs ^ (od & 7)) << 3);
    const float4 a = *(const float4*)sp;
    const float4 c = *(const float4*)(sp + 4);
    float wv[8] = {a.x,a.y,a.z,a.w,c.x,c.y,c.z,c.w};
    #pragma unroll
    for (int j = 0; j < 8; ++j) {
      const unsigned short hh = f2bf(wv[j]);
      vh[j] = (short)hh;
      vl[j] = (short)f2bf(wv[j] - bfh(hh));
    }
  }
  const size_t d = ((size_t)cc * O_pad + od) * 64 + qs * 8;
  *(short8*)&dh[(size_t)y * dst_ls + d] = vh;
  *(short8*)&dl[(size_t)y * dst_ls + d] = vl;
}

// ---------------------------------------------------------------------------
// conv1: [128,3] x x[B,N,3] -> h0 nT hi/lo [B][N][128], bn+relu
__global__ __launch_bounds__(256) void k_conv1(
    const float* __restrict__ x, const float* __restrict__ w,
    const float* __restrict__ g, const float* __restrict__ bb,
    unsigned short* __restrict__ h0h, unsigned short* __restrict__ h0l)
{
  const int tid = threadIdx.x;
  const int n = blockIdx.x * 32 + (tid >> 3);
  const int oc = (tid & 7) * 16;
  const int b = blockIdx.y;
  const float x0 = x[((size_t)b * NP + n) * 3 + 0];
  const float x1 = x[((size_t)b * NP + n) * 3 + 1];
  const float x2 = x[((size_t)b * NP + n) * 3 + 2];
  const size_t base = ((size_t)b * NP + n) * 128 + oc;
  #pragma unroll
  for (int half = 0; half < 2; ++half) {
    short8 vh, vl;
    #pragma unroll
    for (int j = 0; j < 8; ++j) {
      const int o = oc + half * 8 + j;
      float v = w[o*3]*x0 + w[o*3+1]*x1 + w[o*3+2]*x2;
      v = v * (g[o] * rsqrtf(1.f + 1e-5f)) + bb[o];
      v = fmaxf(v, 0.f);
      const unsigned short hh = f2bf(v);
      vh[j] = (short)hh;
      vl[j] = (short)f2bf(v - bfh(hh));
    }
    *(short8*)&h0h[base + half * 8] = vh;
    *(short8*)&h0l[base + half * 8] = vl;
  }
}

// ---------------------------------------------------------------------------
// MFMA GEMM. Pre-split weights, XCD-aware swizzle, OT o x (NT*64) n tile.
// 4 waves n-split; W staging register-prefetched + double-buffered LDS, one
// barrier per chunk. APF: register-prefetch A. WLO: keep W lo-plane.
// AHI: read only the A hi-plane. OLO: write the nT lo-plane.
template<int ACT, bool BN, bool RES, bool CNBF, int OT, int NT,
         bool QV = false, bool APF = true, bool WLO = true, bool AHI = false,
         bool OLO = true>
__global__ __launch_bounds__(256) void k_mm(
    const unsigned short* __restrict__ Ah, const unsigned short* __restrict__ Al,
    int ldA, size_t A_bs,
    const unsigned short* __restrict__ Whp, const unsigned short* __restrict__ Wlp,
    int O_pad,
    const float* __restrict__ convb, int convb_bs,
    const float* __restrict__ bng, const float* __restrict__ bnb,
    const unsigned short* __restrict__ Rh, const unsigned short* __restrict__ Rl,
    int ldR, size_t R_bs,
    unsigned short* __restrict__ Onh, unsigned short* __restrict__ Onl,
    int ldON, size_t ON_bs,
    float* __restrict__ Ocn, size_t OCN_bs,
    int O, int Cin)
{
  constexpr int OF = OT / 16;
  constexpr int NTILES = NP / (NT * 64);
  constexpr int CHK = NTILES / 8;
  constexpr int STR = OF * 16 + 8;
  constexpr int LW_US = OT * 64;               // ushorts per W plane
  constexpr int ST_US = 64 * STR;
  constexpr int WBUF = WLO ? 4 * LW_US : 2 * LW_US;
  constexpr int SM_US = (WBUF > 2*ST_US) ? WBUF : 2*ST_US;
  constexpr int PW = OT / 32;                  // short8 per thread per plane

  const int bid = blockIdx.x;
  const int j  = bid >> 3;
  const int nt = (bid & 7) * CHK + (j % CHK);
  const int o0 = (j / CHK) * OT;
  const int n0 = nt * (NT * 64);
  const int b  = blockIdx.y;
  const int tid = threadIdx.x;
  const int w = tid >> 6, lane = tid & 63, lo = lane & 15, hi = lane >> 4;

  __shared__ __align__(16) unsigned short smem[SM_US];
  unsigned short* sTh = smem;                  // union: epilogue only
  unsigned short* sTl = smem + ST_US;

  const unsigned short* Ahb = Ah + (size_t)b * A_bs;
  const unsigned short* Alb = Al + (size_t)b * A_bs;

  f32x4 acc[NT][OF];
  #pragma unroll
  for (int nf = 0; nf < NT; ++nf)
    #pragma unroll
    for (int of = 0; of < OF; ++of) acc[nf][of] = (f32x4){0.f,0.f,0.f,0.f};

  const int nw = n0 + w * (NT * 16);

  short8 wrh[PW], wrl[PW];
  short8 a0h[2][NT], a0l[2][NT], a1h[2][NT], a1l[2][NT];

  auto loadW = [&](int ci) {
    const size_t wb = ((size_t)ci * O_pad + o0) * 64;
    #pragma unroll
    for (int q = 0; q < PW; ++q) {
      const int cid = tid + q * 256;
      wrh[q] = ld8(Whp + wb + (size_t)cid * 8);
      if constexpr (WLO) wrl[q] = ld8(Wlp + wb + (size_t)cid * 8);
    }
  };
  auto writeW = [&](unsigned short* bWh, unsigned short* bWl) {
    #pragma unroll
    for (int q = 0; q < PW; ++q) {
      const int cid = tid + q * 256;
      *(short8*)&bWh[cid * 8] = wrh[q];
      if constexpr (WLO) *(short8*)&bWl[cid * 8] = wrl[q];
    }
  };

#define LOAD_A(AH, AL, C0)                                             \
  { _Pragma("unroll")                                                  \
    for (int ks = 0; ks < 2; ++ks) {                                   \
      _Pragma("unroll")                                                \
      for (int nf = 0; nf < NT; ++nf) {                                \
        const int n = nw + nf * 16 + lo;                               \
        const size_t idx = (size_t)n * ldA + (C0) + ks * 32 + hi * 8;  \
        AH[ks][nf] = ld8(Ahb + idx);                                   \
        if constexpr (!AHI) AL[ks][nf] = ld8(Alb + idx);               \
      }                                                                \
    } }

#define COMPUTE(BWH, BWL, AHc, ALc)                                    \
  { _Pragma("unroll")                                                  \
    for (int ks = 0; ks < 2; ++ks) {                                   \
      _Pragma("unroll")                                                \
      for (int of = 0; of < OF; ++of) {                                \
        const int row = of * 16 + lo;                                  \
        const int qs = (ks * 4 + hi) ^ (row & 7);                      \
        const short8 bh = ld8(&(BWH)[row * 64 + qs * 8]);              \
        _Pragma("unroll")                                              \
        for (int nf = 0; nf < NT; ++nf)                                \
          acc[nf][of] = MFMA_BF16(AHc[ks][nf], bh, acc[nf][of], 0,0,0);\
        if constexpr (WLO) {                                           \
          const short8 bl = ld8(&(BWL)[row * 64 + qs * 8]);            \
          _Pragma("unroll")                                            \
          for (int nf = 0; nf < NT; ++nf)                              \
            acc[nf][of] = MFMA_BF16(AHc[ks][nf], bl, acc[nf][of],0,0,0);\
        }                                                              \
        if constexpr (!AHI) {                                          \
          _Pragma("unroll")                                            \
          for (int nf = 0; nf < NT; ++nf)                              \
            acc[nf][of] = MFMA_BF16(ALc[ks][nf], bh, acc[nf][of],0,0,0);\
        }                                                              \
      }                                                                \
    } }

  // preload chunk 0
  loadW(0);
  if constexpr (APF) { LOAD_A(a0h, a0l, 0); }

  const int nch = Cin >> 6;                    // even by construction
  for (int cc = 0; cc < nch; cc += 2) {
    // even chunk -> LDS buffer 0
    {
      unsigned short* bWh = smem;
      unsigned short* bWl = WLO ? smem + LW_US : smem;
      writeW(bWh, bWl);
      loadW(cc + 1);                           // always valid (nch even)
      if constexpr (APF) { LOAD_A(a1h, a1l, (cc + 1) * 64); }
      __syncthreads();
      if constexpr (!APF) { LOAD_A(a0h, a0l, cc * 64); }
      COMPUTE(bWh, bWl, a0h, a0l);
    }
    // odd chunk -> LDS buffer 1
    {
      unsigned short* bWh = smem + (WLO ? 2 * LW_US : LW_US);
      unsigned short* bWl = WLO ? bWh + LW_US : bWh;
      writeW(bWh, bWl);
      if (cc + 2 < nch) {
        loadW(cc + 2);
        if constexpr (APF) { LOAD_A(a0h, a0l, (cc + 2) * 64); }
      }
      __syncthreads();
      if constexpr (!APF) { LOAD_A(a1h, a1l, (cc + 1) * 64); }
      COMPUTE(bWh, bWl, a1h, a1l);
    }
  }
#undef LOAD_A
#undef COMPUTE

  // ---- CN outputs: packed r-quad stores, no LDS
  if (Ocn && (!QV || o0 >= 32)) {
    #pragma unroll
    for (int of = 0; of < OF; ++of) {
      const int o = o0 + of * 16 + lo;
      if (o < O) {
        const int oe = QV ? (o - 32) : o;
        const float cb = convb ? convb[(size_t)b * convb_bs + oe] : 0.f;
        float sg = 0.f, sb = 0.f;
        if (BN) { sg = bng[oe] * rsqrtf(1.f + 1e-5f); sb = bnb[oe]; }
        #pragma unroll
        for (int nf = 0; nf < NT; ++nf) {
          const int n = nw + nf * 16 + hi * 4;
          float vv[4];
          #pragma unroll
          for (int r = 0; r < 4; ++r) {
            float v = acc[nf][of][r] + cb;
            if (BN) v = v * sg + sb;
            if (ACT == 1) v = fmaxf(v, 0.f);
            if (ACT == 2) v = v > 0.f ? v : 0.2f * v;
            vv[r] = v;
          }
          if (CNBF) {
            ushort4 pk;
            pk.x = f2bf(vv[0]); pk.y = f2bf(vv[1]);
            pk.z = f2bf(vv[2]); pk.w = f2bf(vv[3]);
            *(ushort4*)&((unsigned short*)Ocn)[(size_t)b * OCN_bs + (size_t)oe * NP + n] = pk;
          } else {
            *(float4*)&Ocn[(size_t)b * OCN_bs + (size_t)oe * NP + n] =
                make_float4(vv[0], vv[1], vv[2], vv[3]);
          }
        }
      }
    }
  }

  // ---- nT outputs: LDS transpose per nf-round, 16B-coalesced stores
  if (Onh && (!QV || o0 == 0)) {
    #pragma unroll
    for (int nf = 0; nf < NT; ++nf) {
      __syncthreads();
      #pragma unroll
      for (int of = 0; of < OF; ++of) {
        const int o = o0 + of * 16 + lo;
        const float cb = (convb && !QV) ? convb[(size_t)b * convb_bs + o] : 0.f;
        float sg = 0.f, sb = 0.f;
        if (BN) { sg = bng[o] * rsqrtf(1.f + 1e-5f); sb = bnb[o]; }
        #pragma unroll
        for (int r = 0; r < 4; ++r) {
          float v = acc[nf][of][r] + cb;
          if (BN) v = v * sg + sb;
          if (ACT == 1) v = fmaxf(v, 0.f);
          if (ACT == 2) v = v > 0.f ? v : 0.2f * v;
          const int lrow = w * 16 + hi * 4 + r;
          const unsigned short hh = f2bf(v);
          sTh[lrow * STR + of * 16 + lo] = hh;
          if constexpr (OLO) sTl[lrow * STR + of * 16 + lo] = f2bf(v - bfh(hh));
        }
      }
      __syncthreads();
      for (int c = tid; c < 64 * OF * 2; c += 256) {
        const int lrow = c / (OF * 2);
        const int oc = (c % (OF * 2)) * 8;
        const int n = n0 + (lrow >> 4) * (NT * 16) + nf * 16 + (lrow & 15);
        const int o = o0 + oc;
        short8 hv = *(short8*)&sTh[lrow * STR + oc];
        short8 lv;
        if constexpr (OLO) lv = *(short8*)&sTl[lrow * STR + oc];
        if (RES) {
          const short8 rhv = ld8(Rh + (size_t)b * R_bs + (size_t)n * ldR + o);
          const short8 rlv = ld8(Rl + (size_t)b * R_bs + (size_t)n * ldR + o);
          #pragma unroll
          for (int jj = 0; jj < 8; ++jj) {
            float v = bf2f((unsigned short)hv[jj], (unsigned short)lv[jj])
                    + bf2f((unsigned short)rhv[jj], (unsigned short)rlv[jj]);
            const unsigned short hh2 = f2bf(v);
            hv[jj] = (short)hh2;
            lv[jj] = (short)f2bf(v - bfh(hh2));
          }
        }
        *(short8*)&Onh[(size_t)b * ON_bs + (size_t)n * ldON + o] = hv;
        if constexpr (OLO)
          *(short8*)&Onl[(size_t)b * ON_bs + (size_t)n * ldON + o] = lv;
      }
    }
  }
}

// ---------------------------------------------------------------------------
// pass A (MFMA): column stats of symmetric E = Q^T Q.
__global__ __launch_bounds__(256) void k_passA(
    const unsigned short* __restrict__ qh, const unsigned short* __restrict__ ql,
    float* __restrict__ pmax, float* __restrict__ psum)
{
  const int m0 = blockIdx.x * 64;
  const int ns = blockIdx.y;
  const int b  = blockIdx.z;
  const int tid = threadIdx.x;
  const int w = tid >> 6, lane = tid & 63, lo = lane & 15, hi = lane >> 4;
  const unsigned short* qhb = qh + (size_t)b * NP * 32;
  const unsigned short* qlb = ql + (size_t)b * NP * 32;

  short8 bh[4], bl[4];
  #pragma unroll
  for (int fj = 0; fj < 4; ++fj) {
    const int m = m0 + fj * 16 + lo;
    bh[fj] = ld8(qhb + (size_t)m * 32 + hi * 8);
    bl[fj] = ld8(qlb + (size_t)m * 32 + hi * 8);
  }
  float mx[4], sm[4];
  #pragma unroll
  for (int fj = 0; fj < 4; ++fj) { mx[fj] = -3e38f; sm[fj] = 0.f; }

  const int nbeg = ns * 512;
  for (int ch = 0; ch < 8; ++ch) {
    const int n0 = nbeg + ch * 64;
    const int nr = n0 + w * 16 + lo;
    const short8 ah = ld8(qhb + (size_t)nr * 32 + hi * 8);
    const short8 al = ld8(qlb + (size_t)nr * 32 + hi * 8);
    #pragma unroll
    for (int fj = 0; fj < 4; ++fj) {
      f32x4 e = MFMA_BF16(ah, bh[fj], (f32x4){0.f,0.f,0.f,0.f}, 0, 0, 0);
      e = MFMA_BF16(ah, bl[fj], e, 0, 0, 0);
      e = MFMA_BF16(al, bh[fj], e, 0, 0, 0);
      const float lm = fmaxf(fmaxf(e[0], e[1]), fmaxf(e[2], e[3]));
      const float nm = fmaxf(mx[fj], lm);
      sm[fj] = sm[fj] * __expf(mx[fj] - nm)
             + __expf(e[0]-nm) + __expf(e[1]-nm) + __expf(e[2]-nm) + __expf(e[3]-nm);
      mx[fj] = nm;
    }
  }
  #pragma unroll
  for (int fj = 0; fj < 4; ++fj) {
    #pragma unroll
    for (int off = 16; off <= 32; off <<= 1) {
      const float om = __shfl_down(mx[fj], off, 64);
      const float os = __shfl_down(sm[fj], off, 64);
      const float nm = fmaxf(mx[fj], om);
      sm[fj] = sm[fj] * __expf(mx[fj] - nm) + os * __expf(om - nm);
      mx[fj] = nm;
    }
  }
  __shared__ float wmx[4][64], wsm[4][64];
  if (hi == 0) {
    #pragma unroll
    for (int fj = 0; fj < 4; ++fj) {
      wmx[w][fj * 16 + lo] = mx[fj];
      wsm[w][fj * 16 + lo] = sm[fj];
    }
  }
  __syncthreads();
  if (tid < 64) {
    float fm = wmx[0][tid], fs = wsm[0][tid];
    #pragma unroll
    for (int w2 = 1; w2 < 4; ++w2) {
      const float om = wmx[w2][tid], os = wsm[w2][tid];
      const float nm = fmaxf(fm, om);
      fs = fs * __expf(fm - nm) + os * __expf(om - nm);
      fm = nm;
    }
    pmax[((size_t)b * 8 + ns) * NP + m0 + tid] = fm;
    psum[((size_t)b * 8 + ns) * NP + m0 + tid] = fs;
  }
}

// ---------------------------------------------------------------------------
// pass B (MFMA): combineA inlined; 8-way n-split; bf16 ypart partials.
__global__ __launch_bounds__(256) void k_passB(
    const unsigned short* __restrict__ qh, const unsigned short* __restrict__ ql,
    const unsigned short* __restrict__ vbf,
    const float* __restrict__ pmax, const float* __restrict__ psum,
    unsigned short* __restrict__ ypart, float* __restrict__ csp)
{
  const int m0 = blockIdx.x * 64;
  const int ns = blockIdx.y;            // 0..7
  const int b  = blockIdx.z;
  const int tid = threadIdx.x;
  const int w = tid >> 6, lane = tid & 63, lo = lane & 15, hi = lane >> 4;
  const unsigned short* qhb = qh + (size_t)b * NP * 32;
  const unsigned short* qlb = ql + (size_t)b * NP * 32;
  const unsigned short* vbb = vbf + (size_t)b * 128 * NP;

  __shared__ __align__(16) unsigned short Pt[2][64 * 64];
  __shared__ float csred[4][64];
  __shared__ float rm_l[512], ri_l[512];

  const int nbeg = ns * 512;
  {
    const int n2 = tid * 2;
    #pragma unroll
    for (int k = 0; k < 2; ++k) {
      const int n = nbeg + n2 + k;
      float mx = -3e38f;
      #pragma unroll
      for (int s = 0; s < 8; ++s)
        mx = fmaxf(mx, pmax[((size_t)b*8 + s) * NP + n]);
      float sm = 0.f;
      #pragma unroll
      for (int s = 0; s < 8; ++s)
        sm += psum[((size_t)b*8 + s) * NP + n] * __expf(pmax[((size_t)b*8 + s) * NP + n] - mx);
      rm_l[n2 + k] = mx;
      ri_l[n2 + k] = 1.f / sm;
    }
  }

  short8 bh[4], bl[4];
  #pragma unroll
  for (int fj = 0; fj < 4; ++fj) {
    const int m = m0 + fj * 16 + lo;
    bh[fj] = ld8(qhb + (size_t)m * 32 + hi * 8);
    bl[fj] = ld8(qlb + (size_t)m * 32 + hi * 8);
  }
  f32x4 yacc[2][4];
  #pragma unroll
  for (int cf = 0; cf < 2; ++cf)
    #pragma unroll
    for (int fj = 0; fj < 4; ++fj) yacc[cf][fj] = (f32x4){0.f,0.f,0.f,0.f};
  float cs[4] = {0.f, 0.f, 0.f, 0.f};

  const int swz = (lo & 7) << 3;
  const int c0 = w * 32;
  __syncthreads();   // rm_l/ri_l ready
  for (int ch = 0; ch < 8; ++ch) {
    unsigned short* Ptc = &Pt[ch & 1][0];
    const int n0 = nbeg + ch * 64;
    const int nr = n0 + w * 16 + lo;
    const short8 ah = ld8(qhb + (size_t)nr * 32 + hi * 8);
    const short8 al = ld8(qlb + (size_t)nr * 32 + hi * 8);
    f32x4 e[4];
    #pragma unroll
    for (int fj = 0; fj < 4; ++fj) {
      e[fj] = MFMA_BF16(ah, bh[fj], (f32x4){0.f,0.f,0.f,0.f}, 0, 0, 0);
      e[fj] = MFMA_BF16(ah, bl[fj], e[fj], 0, 0, 0);
      e[fj] = MFMA_BF16(al, bh[fj], e[fj], 0, 0, 0);
    }
    float rmv[4], riv[4];
    #pragma unroll
    for (int r = 0; r < 4; ++r) {
      const int nl = ch * 64 + w * 16 + hi * 4 + r;
      rmv[r] = rm_l[nl];
      riv[r] = ri_l[nl];
    }
    #pragma unroll
    for (int fj = 0; fj < 4; ++fj) {
      float p[4];
      #pragma unroll
      for (int r = 0; r < 4; ++r) p[r] = __expf(e[fj][r] - rmv[r]) * riv[r];
      cs[fj] += p[0] + p[1] + p[2] + p[3];
      ushort4 pk;
      pk.x = f2bf(p[0]); pk.y = f2bf(p[1]); pk.z = f2bf(p[2]); pk.w = f2bf(p[3]);
      const int row = fj * 16 + lo;
      const int col = (w * 16 + hi * 4) ^ swz;
      *(ushort4*)&Ptc[row * 64 + col] = pk;
    }
    short8 vfrag[2][2];
    #pragma unroll
    for (int cf = 0; cf < 2; ++cf)
      #pragma unroll
      for (int ks = 0; ks < 2; ++ks)
        vfrag[cf][ks] = ld8(vbb + (size_t)(c0 + cf*16 + lo) * NP + n0 + ks*32 + hi*8);
    __syncthreads();
    #pragma unroll
    for (int ks = 0; ks < 2; ++ks) {
      #pragma unroll
      for (int fj = 0; fj < 4; ++fj) {
        const int row = fj * 16 + lo;
        const int col = (ks * 32 + hi * 8) ^ swz;
        const short8 pf = ld8(&Ptc[row * 64 + col]);
        #pragma unroll
        for (int cf = 0; cf < 2; ++cf)
          yacc[cf][fj] = MFMA_BF16(vfrag[cf][ks], pf, yacc[cf][fj], 0, 0, 0);
      }
    }
  }
  // ---- write Y partials as bf16 (halved traffic)
  unsigned short* yp = ypart + ((size_t)b * 8 + ns) * NP * 128;
  #pragma unroll
  for (int cf = 0; cf < 2; ++cf)
    #pragma unroll
    for (int fj = 0; fj < 4; ++fj) {
      const int m = m0 + fj * 16 + lo;
      const int c = w * 32 + cf * 16 + hi * 4;
      ushort4 pk;
      pk.x = f2bf(yacc[cf][fj][0]); pk.y = f2bf(yacc[cf][fj][1]);
      pk.z = f2bf(yacc[cf][fj][2]); pk.w = f2bf(yacc[cf][fj][3]);
      *(ushort4*)&yp[(size_t)m * 128 + c] = pk;
    }
  #pragma unroll
  for (int fj = 0; fj < 4; ++fj) {
    cs[fj] += __shfl_down(cs[fj], 16, 64);
    cs[fj] += __shfl_down(cs[fj], 32, 64);
  }
  __syncthreads();
  if (hi == 0) {
    #pragma unroll
    for (int fj = 0; fj < 4; ++fj) csred[w][fj * 16 + lo] = cs[fj];
  }
  __syncthreads();
  if (tid < 64)
    csp[((size_t)b * 8 + ns) * NP + m0 + tid] =
        csred[0][tid] + csred[1][tid] + csred[2][tid] + csred[3][tid];
}

// combineB: d = h - (sum_ns y)/(1e-9 + sum_ns cs), emitted as nT hi/lo [N][128]
__global__ __launch_bounds__(256) void k_combineB(
    const unsigned short* __restrict__ ypart, const float* __restrict__ csp,
    const unsigned short* __restrict__ hinh, const unsigned short* __restrict__ hinl,
    int ldH, size_t H_bs,
    unsigned short* __restrict__ dh, unsigned short* __restrict__ dl)
{
  const size_t i = (size_t)blockIdx.x * 256 + threadIdx.x;  // < B*NP*128
  const int c = (int)(i & 127);
  const int n = (int)((i >> 7) & (NP - 1));
  const int b = (int)(i >> 19);
  float s = 1e-9f, y = 0.f;
  #pragma unroll
  for (int ns = 0; ns < 8; ++ns) {
    y += bfh(ypart[(((size_t)b*8 + ns) * NP + n) * 128 + c]);
    s += csp[((size_t)b*8 + ns) * NP + n];
  }
  const float h = bf2f(hinh[(size_t)b * H_bs + (size_t)n * ldH + c],
                       hinl[(size_t)b * H_bs + (size_t)n * ldH + c]);
  const float d = h - y / s;
  const unsigned short hh = f2bf(d);
  dh[i] = hh;
  dl[i] = f2bf(d - bfh(hh));
}

// ---------------------------------------------------------------------------
// per-channel max/mean of fuse output, hi-plane-only nT [N][1024].
__global__ __launch_bounds__(256) void k_maxavg_p(
    const unsigned short* __restrict__ fh,
    float* __restrict__ pmx, float* __restrict__ psm)
{
  const int tid = threadIdx.x;
  const int c4 = (tid & 15) * 4;
  const int st = tid >> 4;
  const int o0 = blockIdx.x * 64;
  const int nsp = blockIdx.y;
  const int b = blockIdx.z;
  const int nbeg = nsp * 256;
  const unsigned short* fhb = fh + (size_t)b * NP * 1024 + o0 + c4;
  float mx[4] = {-3e38f,-3e38f,-3e38f,-3e38f}, sm[4] = {0.f,0.f,0.f,0.f};
  #pragma unroll 4
  for (int n = nbeg + st; n < nbeg + 256; n += 16) {
    const ushort4 vh = *(const ushort4*)(fhb + (size_t)n * 1024);
    const float v0 = bfh(vh.x), v1 = bfh(vh.y);
    const float v2 = bfh(vh.z), v3 = bfh(vh.w);
    mx[0] = fmaxf(mx[0], v0); sm[0] += v0;
    mx[1] = fmaxf(mx[1], v1); sm[1] += v1;
    mx[2] = fmaxf(mx[2], v2); sm[2] += v2;
    mx[3] = fmaxf(mx[3], v3); sm[3] += v3;
  }
  __shared__ float smx[16][64], ssm[16][64];
  #pragma unroll
  for (int j = 0; j < 4; ++j) { smx[st][c4 + j] = mx[j]; ssm[st][c4 + j] = sm[j]; }
  __syncthreads();
  if (tid < 64) {
    float m = -3e38f, s = 0.f;
    #pragma unroll
    for (int k = 0; k < 16; ++k) { m = fmaxf(m, smx[k][tid]); s += ssm[k][tid]; }
    pmx[((size_t)b * 16 + nsp) * 1024 + o0 + tid] = m;
    psm[((size_t)b * 16 + nsp) * 1024 + o0 + tid] = s;
  }
}

__global__ __launch_bounds__(256) void k_maxavg_c(
    const float* __restrict__ pmx, const float* __restrict__ psm,
    float* __restrict__ xm, float* __restrict__ xa)
{
  const int i = blockIdx.x * 256 + threadIdx.x;   // < B*1024
  const int c = i & 1023;
  const int b = i >> 10;
  float m = -3e38f, s = 0.f;
  #pragma unroll
  for (int k = 0; k < 16; ++k) {
    m = fmaxf(m, pmx[((size_t)b * 16 + k) * 1024 + c]);
    s += psm[((size_t)b * 16 + k) * 1024 + c];
  }
  xm[i] = m;
  xa[i] = s * (1.f / NP);
}

__global__ void k_cls(const float* __restrict__ cl, const float* __restrict__ W,
                      const float* __restrict__ g, const float* __restrict__ bb,
                      float* __restrict__ clsf)
{
  const int t = threadIdx.x;
  const int b = t >> 6, o = t & 63;
  float a = 0.f;
  #pragma unroll
  for (int j = 0; j < 16; ++j) a += W[o * 16 + j] * cl[b * 16 + j];
  a = a * (g[o] * rsqrtf(1.f + 1e-5f)) + bb[o];
  clsf[b * 64 + o] = a > 0.f ? a : 0.2f * a;
}

__global__ __launch_bounds__(256) void k_gbias(
    const float* __restrict__ W1, const float* __restrict__ xm,
    const float* __restrict__ xa, const float* __restrict__ clsf,
    const float* __restrict__ c1b, float* __restrict__ gb)
{
  const int o = blockIdx.x, b = blockIdx.y;
  float a = 0.f;
  for (int j = threadIdx.x; j < 2112; j += 256) {
    const float gv = (j < 1024) ? xm[b * 1024 + j]
                   : (j < 2048) ? xa[b * 1024 + (j - 1024)]
                                : clsf[b * 64 + (j - 2048)];
    a += W1[(size_t)o * 3136 + 1024 + j] * gv;
  }
  a = wsum(a);
  __shared__ float red[4];
  const int w = threadIdx.x >> 6;
  if ((threadIdx.x & 63) == 0) red[w] = a;
  __syncthreads();
  if (threadIdx.x == 0) gb[b * 512 + o] = red[0] + red[1] + red[2] + red[3] + c1b[o];
}

// ---------------------------------------------------------------------------
extern "C" void kernel_launch(void* const* d_in, const int* in_sizes, int n_in,
                              void* d_out, int out_size, void* d_ws, size_t ws_size,
                              hipStream_t stream)
{
  const float* x        = (const float*)d_in[0];
  const float* cls_lab  = (const float*)d_in[1];
  const float* conv1_w  = (const float*)d_in[2];
  const float* bn1_g    = (const float*)d_in[3];
  const float* bn1_b    = (const float*)d_in[4];
  const float* conv2_w  = (const float*)d_in[5];
  const float* bn2_g    = (const float*)d_in[6];
  const float* bn2_b    = (const float*)d_in[7];
  const float* sa_qk_w  = (const float*)d_in[8];
  const float* sa_v_w   = (const float*)d_in[9];
  const float* sa_v_b   = (const float*)d_in[10];
  const float* sa_t_w   = (const float*)d_in[11];
  const float* sa_t_b   = (const float*)d_in[12];
  const float* sa_bn_g  = (const float*)d_in[13];
  const float* sa_bn_b  = (const float*)d_in[14];
  const float* fuse_w   = (const float*)d_in[15];
  const float* fuse_g   = (const float*)d_in[16];
  const float* fuse_b   = (const float*)d_in[17];
  const float* label_w  = (const float*)d_in[18];
  const float* label_g  = (const float*)d_in[19];
  const float* label_b  = (const float*)d_in[20];
  const float* c1_w     = (const float*)d_in[21];
  const float* c1_b     = (const float*)d_in[22];
  const float* bns1_g   = (const float*)d_in[23];
  const float* bns1_b   = (const float*)d_in[24];
  const float* c2_w     = (const float*)d_in[25];
  const float* c2_b     = (const float*)d_in[26];
  const float* bns2_g   = (const float*)d_in[27];
  const float* bns2_b   = (const float*)d_in[28];
  const float* c3_w     = (const float*)d_in[29];
  const float* c3_b     = (const float*)d_in[30];
  float* outp = (float*)d_out;

  float* f = (float*)d_ws;
  size_t off = 0;
  auto us = [&](size_t n_ushort) { unsigned short* p = (unsigned short*)(f + off);
                                   off += (n_ushort + 1) / 2; return p; };
  unsigned short* h0h  = us((size_t)BB*NP*128);
  unsigned short* h0l  = us((size_t)BB*NP*128);
  unsigned short* h1h  = us((size_t)BB*NP*128);
  unsigned short* h1l  = us((size_t)BB*NP*128);
  unsigned short* hch  = us((size_t)BB*NP*512);
  unsigned short* hcl  = us((size_t)BB*NP*512);
  unsigned short* qTh  = us((size_t)BB*NP*32);
  unsigned short* qTl  = us((size_t)BB*NP*32);
  unsigned short* vb   = us((size_t)BB*128*NP);
  unsigned short* dhb  = us((size_t)BB*NP*128);
  unsigned short* dlb  = us((size_t)BB*NP*128);
  // pre-split weight buffers (persist across whole call)
  unsigned short* wc2h = us(2*128*64);        unsigned short* wc2l = us(2*128*64);
  unsigned short* wqvh = us(4*2*160*64);      unsigned short* wqvl = us(4*2*160*64);
  unsigned short* wth  = us(4*2*128*64);      unsigned short* wtl  = us(4*2*128*64);
  unsigned short* wfh  = us(8*1024*64);       unsigned short* wfl  = us(8*1024*64);
  unsigned short* w1h  = us(16*512*64);       unsigned short* w1l  = us(16*512*64);
  unsigned short* w2h  = us(8*256*64);        unsigned short* w2l  = us(8*256*64);
  unsigned short* w3h  = us(4*64*64);         unsigned short* w3l  = us(4*64*64);
  float* pmax  = f + off; off += (size_t)BB*8*NP;
  float* psum  = f + off; off += (size_t)BB*8*NP;
  float* csp   = f + off; off += (size_t)BB*8*NP;
  float* pmx   = f + off; off += (size_t)BB*16*1024;
  float* psm   = f + off; off += (size_t)BB*16*1024;
  float* xm    = f + off; off += (size_t)BB*1024;
  float* xa    = f + off; off += (size_t)BB*1024;
  float* clsf  = f + off; off += (size_t)BB*64;
  float* gb    = f + off; off += (size_t)BB*512;
  off = (off + 255) & ~(size_t)255;
  unsigned short* ypart = (unsigned short*)(f + off);   // BB*8*NP*128 ushorts
  unsigned short* fuh = ypart;                          // alias (disjoint in time)
  unsigned short* o1h = fuh + (size_t)BB*NP*1024;
  unsigned short* o2h = o1h + (size_t)BB*NP*512;

  const dim3 blk(256);

  // ---- weight pre-split (LDS-ready layout)
  k_wsplit<<<dim3(8,1),   blk, 0, stream>>>(conv2_w, 0, wc2h, wc2l, 0, 128, 128, 128, 0, 128, 128);
  k_wsplit<<<dim3(2,4),   blk, 0, stream>>>(sa_qk_w, 32*128, wqvh, wqvl, 2*160*64, 32, 32, 160, 0, 128, 128);
  k_wsplit<<<dim3(8,4),   blk, 0, stream>>>(sa_v_w, 128*128, wqvh, wqvl, 2*160*64, 128, 128, 160, 32, 128, 128);
  k_wsplit<<<dim3(8,4),   blk, 0, stream>>>(sa_t_w, 128*128, wth, wtl, 2*128*64, 128, 128, 128, 0, 128, 128);
  k_wsplit<<<dim3(256,1), blk, 0, stream>>>(fuse_w, 0, wfh, wfl, 0, 1024, 1024, 1024, 0, 512, 512);
  k_wsplit<<<dim3(256,1), blk, 0, stream>>>(c1_w, 0, w1h, w1l, 0, 512, 512, 512, 0, 1024, 3136);
  k_wsplit<<<dim3(64,1),  blk, 0, stream>>>(c2_w, 0, w2h, w2l, 0, 256, 256, 256, 0, 512, 512);
  k_wsplit<<<dim3(8,1),   blk, 0, stream>>>(c3_w, 0, w3h, w3l, 0, 50, 64, 64, 0, 256, 256);

  k_conv1<<<dim3(128, BB), blk, 0, stream>>>(x, conv1_w, bn1_g, bn1_b, h0h, h0l);

  // conv2: 128<-128, bn+relu -> h1 nT  (full precision)
  k_mm<1,true,false,false,32,1><<<dim3(256,BB), blk, 0, stream>>>(
      h0h, h0l, 128, (size_t)NP*128, wc2h, wc2l, 128, nullptr, 0, bn2_g, bn2_b,
      nullptr, nullptr, 0, 0, h1h, h1l, 128, (size_t)NP*128, nullptr, 0, 128, 128);

  for (int i = 0; i < 4; ++i) {
    const unsigned short* hinh = (i == 0) ? h1h : hch + (size_t)(i-1)*128;
    const unsigned short* hinl = (i == 0) ? h1l : hcl + (size_t)(i-1)*128;
    const int ldH = (i == 0) ? 128 : 512;
    const size_t H_bs = (size_t)NP * ldH;

    // fused q+v: O=160 stacked; q rows -> qT nT, v rows -> bf16 CN + bias
    k_mm<0,false,false,true,32,1,true><<<dim3(320,BB), blk, 0, stream>>>(
        hinh, hinl, ldH, H_bs, wqvh + (size_t)i*2*160*64, wqvl + (size_t)i*2*160*64, 160,
        sa_v_b + (size_t)i*128, 0, nullptr, nullptr,
        nullptr, nullptr, 0, 0,
        qTh, qTl, 32, (size_t)NP*32,
        (float*)vb, (size_t)128*NP, 160, 128);

    k_passA<<<dim3(64,8,BB), blk, 0, stream>>>(qTh, qTl, pmax, psum);
    k_passB<<<dim3(64,8,BB), blk, 0, stream>>>(qTh, qTl, vb, pmax, psum, ypart, csp);
    k_combineB<<<dim3(BB*NP*128/256), blk, 0, stream>>>(
        ypart, csp, hinh, hinl, ldH, H_bs, dhb, dlb);

    // t: 128<-128 on (h - x_r), + t_b, bn, relu, + residual h  (W-hi only)
    k_mm<1,true,true,false,32,1,false,true,false><<<dim3(256,BB), blk, 0, stream>>>(
        dhb, dlb, 128, (size_t)NP*128, wth + (size_t)i*2*128*64, wtl + (size_t)i*2*128*64, 128,
        sa_t_b + (size_t)i*128, 0, sa_bn_g + (size_t)i*128, sa_bn_b + (size_t)i*128,
        hinh, hinl, ldH, H_bs,
        hch + (size_t)i*128, hcl + (size_t)i*128, 512, (size_t)NP*512,
        nullptr, 0, 128, 128);
  }

  // fuse: 1024<-512, bn + leaky -> fuse nT hi only (pure-bf16 tail)
  k_mm<2,true,false,false,64,2,false,true,false,true,false><<<dim3(512,BB), blk, 0, stream>>>(
      hch, hcl, 512, (size_t)NP*512, wfh, wfl, 1024, nullptr, 0, fuse_g, fuse_b,
      nullptr, nullptr, 0, 0, fuh, nullptr, 1024, (size_t)NP*1024, nullptr, 0, 1024, 512);

  k_maxavg_p<<<dim3(16,16,BB), blk, 0, stream>>>(fuh, pmx, psm);
  k_maxavg_c<<<dim3(BB*1024/256), blk, 0, stream>>>(pmx, psm, xm, xa);
  k_cls<<<dim3(1), dim3(128), 0, stream>>>(cls_lab, label_w, label_g, label_b, clsf);
  k_gbias<<<dim3(512, BB), blk, 0, stream>>>(c1_w, xm, xa, clsf, c1_b, gb);

  // convs1: 512<-1024 (+gb), bn, relu -> out1 hi only (pure-bf16)
  k_mm<1,true,false,false,64,2,false,true,false,true,false><<<dim3(256,BB), blk, 0, stream>>>(
      fuh, fuh, 1024, (size_t)NP*1024, w1h, w1l, 512, gb, 512, bns1_g, bns1_b,
      nullptr, nullptr, 0, 0, o1h, nullptr, 512, (size_t)NP*512, nullptr, 0, 512, 1024);

  // convs2: 256<-512 + c2_b, bn, relu -> out2 hi only (pure-bf16)
  k_mm<1,true,false,false,64,1,false,true,false,true,false><<<dim3(256,BB), blk, 0, stream>>>(
      o1h, o1h, 512, (size_t)NP*512, w2h, w2l, 256, c2_b, 0, bns2_g, bns2_b,
      nullptr, nullptr, 0, 0, o2h, nullptr, 256, (size_t)NP*256, nullptr, 0, 256, 512);

  // convs3: 50<-256 + c3_b -> fp32 [50][N] output (pure-bf16 inputs)
  k_mm<0,false,false,false,64,1,false,true,false,true><<<dim3(64,BB), blk, 0, stream>>>(
      o2h, o2h, 256, (size_t)NP*256, w3h, w3l, 64, c3_b, 0, nullptr, nullptr,
      nullptr, nullptr, 0, 0, nullptr, nullptr, 0, 0,
      outp, (size_t)50*NP, 50, 256);
}